// Round 10
// baseline (252.554 us; speedup 1.0000x reference)
//
#include <hip/hip_runtime.h>
#include <math.h>

namespace {

constexpr int Bn = 8;
constexpr int Sn = 1024;
constexpr int Dn = 256;
constexpr int Mn = Bn * Sn;    // 8192 rows
constexpr int L  = 32;         // chunk length
constexpr int NSEG = Sn / L;   // 32 chunks

typedef __attribute__((ext_vector_type(8))) short short8;   // 8 bf16 (4 VGPRs)
typedef __attribute__((ext_vector_type(4))) float f32x4;    // MFMA acc

__device__ float g_den[Bn * Sn];   // n·q per (b,t); written by compose den-blocks

__device__ __forceinline__ float sigmoidf_(float x) {
    return 1.0f / (1.0f + __expf(-x));
}

__device__ __forceinline__ unsigned short f2bf(float x) {
    unsigned int u = __float_as_uint(x);
    return (unsigned short)((u + 0x7FFF + ((u >> 16) & 1)) >> 16);   // RNE
}
__device__ __forceinline__ float bf2f(unsigned short h) {
    return __uint_as_float(((unsigned int)h) << 16);
}

// ---------------------------------------------------------------------------
// split_xw: one-time fp32 -> bf16 hi/lo split of X, packed {Wq,Wk,Wf,Wi},
// and (new) Wo. Grid 2368 blocks.
// ---------------------------------------------------------------------------
__global__ __launch_bounds__(256) void split_xw(
    const float* __restrict__ X,
    const float* __restrict__ Wq, const float* __restrict__ Wk,
    const float* __restrict__ Wf, const float* __restrict__ Wi,
    const float* __restrict__ Wo,
    unsigned short* __restrict__ Xh, unsigned short* __restrict__ Xl,
    unsigned short* __restrict__ Wh, unsigned short* __restrict__ Wl,
    unsigned short* __restrict__ Woh, unsigned short* __restrict__ Wol)
{
    const int i = blockIdx.x * 256 + threadIdx.x;
    const float4* src;
    unsigned short* dh;
    unsigned short* dl;
    size_t off;
    if (i < 524288) {
        src = (const float4*)X + i;
        dh = Xh; dl = Xl;
        off = (size_t)i * 4;
    } else if (i < 589824) {
        const int j = i - 524288;          // 0..65535
        const int w = j >> 14;             // which weight
        const int r = j & 16383;           // float4 within weight
        const float* Wp = (w == 0) ? Wq : (w == 1) ? Wk : (w == 2) ? Wf : Wi;
        src = (const float4*)Wp + r;
        dh = Wh; dl = Wl;
        off = ((size_t)w << 16) + (size_t)r * 4;
    } else {
        const int j = i - 589824;          // 0..16383
        src = (const float4*)Wo + j;
        dh = Woh; dl = Wol;
        off = (size_t)j * 4;
    }
    const float4 v = *src;
    ushort4 h, l;
    h.x = f2bf(v.x); l.x = f2bf(v.x - bf2f(h.x));
    h.y = f2bf(v.y); l.y = f2bf(v.y - bf2f(h.y));
    h.z = f2bf(v.z); l.z = f2bf(v.z - bf2f(h.z));
    h.w = f2bf(v.w); l.w = f2bf(v.w - bf2f(h.w));
    *(ushort4*)(dh + off) = h;
    *(ushort4*)(dl + off) = l;
}

// ---------------------------------------------------------------------------
// proj_gemm2: pure-bf16 MFMA x3 projection GEMM (r5 exact, 201.5us config).
// 128x128 tile, BK=32, register prefetch of next K-tile.
// ---------------------------------------------------------------------------
__global__ __launch_bounds__(256) void proj_gemm2(
    const unsigned short* __restrict__ Xh, const unsigned short* __restrict__ Xl,
    const unsigned short* __restrict__ Wh, const unsigned short* __restrict__ Wl,
    const float* __restrict__ b0, const float* __restrict__ b1,
    const float* __restrict__ b2, const float* __restrict__ b3,
    float* __restrict__ Y0, float* __restrict__ Y1,
    float* __restrict__ Y2, float* __restrict__ Y3)
{
    __shared__ unsigned short Ahs[128][40];
    __shared__ unsigned short Als[128][40];
    __shared__ unsigned short Bhs[128][40];
    __shared__ unsigned short Bls[128][40];

    const int tid = threadIdx.x;
    const int mb  = blockIdx.x * 128;
    const int nbg = blockIdx.y;            // 0..7
    const int widx = nbg >> 1;
    const int ro   = (nbg & 1) * 128;

    const float* bsel = (widx == 0) ? b0 : (widx == 1) ? b1 : (widx == 2) ? b2 : b3;
    float*       Ysel = (widx == 0) ? Y0 : (widx == 1) ? Y1 : (widx == 2) ? Y2 : Y3;

    const int lane = tid & 63;
    const int wv   = tid >> 6;
    const int wm   = (wv >> 1) * 64;
    const int wn   = (wv & 1) * 64;
    const int quad = lane >> 4;
    const int l16  = lane & 15;
    const int srow = tid >> 1;
    const int skq  = (tid & 1) * 16;

    const size_t abase = (size_t)(mb + srow) * Dn + skq;
    const size_t bbase = (size_t)(nbg * 128 + srow) * Dn + skq;

    f32x4 acc[4][4];
    #pragma unroll
    for (int mt = 0; mt < 4; ++mt)
        #pragma unroll
        for (int nt = 0; nt < 4; ++nt)
            acc[mt][nt] = (f32x4){0.f, 0.f, 0.f, 0.f};

    short8 pah0, pah1, pal0, pal1, pbh0, pbh1, pbl0, pbl1;
    pah0 = *(const short8*)(Xh + abase);     pah1 = *(const short8*)(Xh + abase + 8);
    pal0 = *(const short8*)(Xl + abase);     pal1 = *(const short8*)(Xl + abase + 8);
    pbh0 = *(const short8*)(Wh + bbase);     pbh1 = *(const short8*)(Wh + bbase + 8);
    pbl0 = *(const short8*)(Wl + bbase);     pbl1 = *(const short8*)(Wl + bbase + 8);

    for (int k0 = 0; k0 < Dn; k0 += 32) {
        __syncthreads();
        *(short8*)&Ahs[srow][skq]     = pah0;
        *(short8*)&Ahs[srow][skq + 8] = pah1;
        *(short8*)&Als[srow][skq]     = pal0;
        *(short8*)&Als[srow][skq + 8] = pal1;
        *(short8*)&Bhs[srow][skq]     = pbh0;
        *(short8*)&Bhs[srow][skq + 8] = pbh1;
        *(short8*)&Bls[srow][skq]     = pbl0;
        *(short8*)&Bls[srow][skq + 8] = pbl1;
        __syncthreads();

        if (k0 + 32 < Dn) {
            const size_t ka = abase + k0 + 32;
            const size_t kb = bbase + k0 + 32;
            pah0 = *(const short8*)(Xh + ka); pah1 = *(const short8*)(Xh + ka + 8);
            pal0 = *(const short8*)(Xl + ka); pal1 = *(const short8*)(Xl + ka + 8);
            pbh0 = *(const short8*)(Wh + kb); pbh1 = *(const short8*)(Wh + kb + 8);
            pbl0 = *(const short8*)(Wl + kb); pbl1 = *(const short8*)(Wl + kb + 8);
        }

        short8 afh[4], afl[4];
        #pragma unroll
        for (int mt = 0; mt < 4; ++mt) {
            const int row = wm + mt * 16 + l16;
            afh[mt] = *(const short8*)&Ahs[row][quad * 8];
            afl[mt] = *(const short8*)&Als[row][quad * 8];
        }
        #pragma unroll
        for (int nt = 0; nt < 4; ++nt) {
            const int row = wn + nt * 16 + l16;
            const short8 bfh = *(const short8*)&Bhs[row][quad * 8];
            const short8 bfl = *(const short8*)&Bls[row][quad * 8];
            #pragma unroll
            for (int mt = 0; mt < 4; ++mt) {
                acc[mt][nt] = __builtin_amdgcn_mfma_f32_16x16x32_bf16(
                    afh[mt], bfh, acc[mt][nt], 0, 0, 0);
                acc[mt][nt] = __builtin_amdgcn_mfma_f32_16x16x32_bf16(
                    afh[mt], bfl, acc[mt][nt], 0, 0, 0);
                acc[mt][nt] = __builtin_amdgcn_mfma_f32_16x16x32_bf16(
                    afl[mt], bfh, acc[mt][nt], 0, 0, 0);
            }
        }
    }

    #pragma unroll
    for (int nt = 0; nt < 4; ++nt) {
        const int col = ro + wn + nt * 16 + l16;
        const float bv = bsel[col];
        #pragma unroll
        for (int mt = 0; mt < 4; ++mt) {
            const int rowb = mb + wm + mt * 16 + quad * 4;
            #pragma unroll
            for (int r = 0; r < 4; ++r) {
                float v = acc[mt][nt][r] + bv;
                if (widx == 2)      v = sigmoidf_(v);
                else if (widx == 3) v = __expf(v);
                Ysel[(size_t)(rowb + r) * Dn + col] = v;
            }
        }
    }
}

// ---------------------------------------------------------------------------
// out_gemm2: pure-bf16 MFMA x3 output GEMM (r5 exact). 64x64, grid (128,4).
// ---------------------------------------------------------------------------
__global__ __launch_bounds__(256) void out_gemm2(
    const unsigned short* __restrict__ Ph, const unsigned short* __restrict__ Pl,
    const unsigned short* __restrict__ Woh, const unsigned short* __restrict__ Wol,
    const float* __restrict__ bias, float* __restrict__ Y)
{
    __shared__ unsigned short Ahs[64][40];
    __shared__ unsigned short Als[64][40];
    __shared__ unsigned short Bhs[64][40];
    __shared__ unsigned short Bls[64][40];

    const int tid = threadIdx.x;
    const int mb  = blockIdx.x * 64;
    const int nb  = blockIdx.y * 64;

    const int lane = tid & 63;
    const int wv   = tid >> 6;
    const int wm   = (wv >> 1) * 32;
    const int wn   = (wv & 1) * 32;
    const int quad = lane >> 4;
    const int l16  = lane & 15;
    const int srow = tid >> 2;
    const int skq  = (tid & 3) * 8;

    const size_t abase = (size_t)(mb + srow) * Dn + skq;
    const size_t bbase = (size_t)(nb + srow) * Dn + skq;

    f32x4 acc[2][2];
    #pragma unroll
    for (int mt = 0; mt < 2; ++mt)
        #pragma unroll
        for (int nt = 0; nt < 2; ++nt)
            acc[mt][nt] = (f32x4){0.f, 0.f, 0.f, 0.f};

    short8 pah, pal, pbh, pbl;
    pah = *(const short8*)(Ph  + abase);
    pal = *(const short8*)(Pl  + abase);
    pbh = *(const short8*)(Woh + bbase);
    pbl = *(const short8*)(Wol + bbase);

    for (int k0 = 0; k0 < Dn; k0 += 32) {
        __syncthreads();
        *(short8*)&Ahs[srow][skq] = pah;
        *(short8*)&Als[srow][skq] = pal;
        *(short8*)&Bhs[srow][skq] = pbh;
        *(short8*)&Bls[srow][skq] = pbl;
        __syncthreads();

        if (k0 + 32 < Dn) {
            const size_t ka = abase + k0 + 32;
            const size_t kb = bbase + k0 + 32;
            pah = *(const short8*)(Ph  + ka);
            pal = *(const short8*)(Pl  + ka);
            pbh = *(const short8*)(Woh + kb);
            pbl = *(const short8*)(Wol + kb);
        }

        short8 afh[2], afl[2];
        #pragma unroll
        for (int mt = 0; mt < 2; ++mt) {
            const int row = wm + mt * 16 + l16;
            afh[mt] = *(const short8*)&Ahs[row][quad * 8];
            afl[mt] = *(const short8*)&Als[row][quad * 8];
        }
        #pragma unroll
        for (int nt = 0; nt < 2; ++nt) {
            const int row = wn + nt * 16 + l16;
            const short8 bfh = *(const short8*)&Bhs[row][quad * 8];
            const short8 bfl = *(const short8*)&Bls[row][quad * 8];
            #pragma unroll
            for (int mt = 0; mt < 2; ++mt) {
                acc[mt][nt] = __builtin_amdgcn_mfma_f32_16x16x32_bf16(
                    afh[mt], bfh, acc[mt][nt], 0, 0, 0);
                acc[mt][nt] = __builtin_amdgcn_mfma_f32_16x16x32_bf16(
                    afh[mt], bfl, acc[mt][nt], 0, 0, 0);
                acc[mt][nt] = __builtin_amdgcn_mfma_f32_16x16x32_bf16(
                    afl[mt], bfh, acc[mt][nt], 0, 0, 0);
            }
        }
    }

    #pragma unroll
    for (int nt = 0; nt < 2; ++nt) {
        const int col = nb + wn + nt * 16 + l16;
        const float bv = bias[col];
        #pragma unroll
        for (int mt = 0; mt < 2; ++mt) {
            const int rowb = mb + wm + mt * 16 + quad * 4;
            #pragma unroll
            for (int r = 0; r < 4; ++r) {
                Y[(size_t)(rowb + r) * Dn + col] = acc[mt][nt][r] + bv;
            }
        }
    }
}

// ---------------------------------------------------------------------------
// prep (v2): 512 threads, wave-specialized (gate scan || masked QK^T).
// (g_den zero-init removed: den is now plain-stored by compose.)
// ---------------------------------------------------------------------------
__global__ __launch_bounds__(512) void prep(
    const float* __restrict__ Pf, const float* __restrict__ Pi,
    const float* __restrict__ Pk, const float* __restrict__ Pq,
    float* __restrict__ Gc, float* __restrict__ Vt, float* __restrict__ Nt,
    float* __restrict__ Aend, float* __restrict__ un, float* __restrict__ Ssm)
{
    __shared__ float Ks[L][260];   // K chunk, row-major, +4 pad
    __shared__ float Qs[L][260];   // Q chunk

    const int m = blockIdx.x;
    const int b = blockIdx.y;
    const int tid = threadIdx.x;
    const size_t qb = (size_t)b * Sn * Dn + (size_t)m * L * Dn;

    #pragma unroll
    for (int p = 0; p < 4; ++p) {
        const int lin = p * 512 + tid;           // 0..2047
        const int row = lin >> 6;
        const int c4  = (lin & 63) * 4;
        *(float4*)&Ks[row][c4] = *(const float4*)(Pk + qb + (size_t)row * Dn + c4);
    }
    #pragma unroll
    for (int p = 0; p < 4; ++p) {
        const int lin = p * 512 + tid;
        const int row = lin >> 6;
        const int c4  = (lin & 63) * 4;
        *(float4*)&Qs[row][c4] = *(const float4*)(Pq + qb + (size_t)row * Dn + c4);
    }
    __syncthreads();

    if (tid < 256) {
        // ---- phase A: gate scan, thread = column r; f/i batched 8-deep ----
        const int r = tid;
        const size_t base = qb + r;
        float G = 1.0f, Nacc = 0.0f;
        for (int tb = 0; tb < L; tb += 8) {
            float fv[8], iv[8];
            #pragma unroll
            for (int u = 0; u < 8; ++u) {
                fv[u] = Pf[base + (size_t)(tb + u) * Dn];
                iv[u] = Pi[base + (size_t)(tb + u) * Dn];
            }
            #pragma unroll
            for (int u = 0; u < 8; ++u) {
                const int t = tb + u;
                const size_t off = base + (size_t)t * Dn;
                const float kv = Ks[t][r];
                const float vv = Qs[t][r];
                G *= fv[u];
                const float rG = 1.0f / G;
                Gc[off] = G;
                Vt[off] = iv[u] * vv * rG;
                Nacc = fmaf(iv[u] * kv, rG, Nacc);
                Nt[off] = Nacc;
            }
        }
        const size_t s = ((size_t)b * NSEG + m) * Dn + r;
        Aend[s] = G;
        un[s]   = G * Nacc;
    } else {
        // ---- phase B: S = masked QK^T from LDS ----
        const int t2  = tid - 256;
        const int tau = t2 >> 3;
        const int sb0 = t2 & 7;                  // sigma = sb0 + 8j, j=0..3

        float a0 = 0.f, a1 = 0.f, a2 = 0.f, a3 = 0.f;
        #pragma unroll 4
        for (int c = 0; c < Dn; c += 4) {
            const float4 q4 = *(const float4*)&Qs[tau][c];
            const float4 k0 = *(const float4*)&Ks[sb0     ][c];
            const float4 k1 = *(const float4*)&Ks[sb0 +  8][c];
            const float4 k2 = *(const float4*)&Ks[sb0 + 16][c];
            const float4 k3 = *(const float4*)&Ks[sb0 + 24][c];
            a0 += q4.x*k0.x + q4.y*k0.y + q4.z*k0.z + q4.w*k0.w;
            a1 += q4.x*k1.x + q4.y*k1.y + q4.z*k1.z + q4.w*k1.w;
            a2 += q4.x*k2.x + q4.y*k2.y + q4.z*k2.z + q4.w*k2.w;
            a3 += q4.x*k3.x + q4.y*k3.y + q4.z*k3.z + q4.w*k3.w;
        }
        float* outp = Ssm + ((size_t)b * NSEG + m) * L * L + (size_t)tau * L;
        outp[sb0     ] = (sb0      <= tau) ? a0 : 0.0f;
        outp[sb0 +  8] = (sb0 +  8 <= tau) ? a1 : 0.0f;
        outp[sb0 + 16] = (sb0 + 16 <= tau) ? a2 : 0.0f;
        outp[sb0 + 24] = (sb0 + 24 <= tau) ? a3 : 0.0f;
    }
}

// ---------------------------------------------------------------------------
// ut_gemm: UT[b,m][c,r] = Aend[r] * Σ_σ K[σ,c]·Ṽ[σ,r]
// ---------------------------------------------------------------------------
__global__ __launch_bounds__(256) void ut_gemm(
    const float* __restrict__ Pk, const float* __restrict__ Vt,
    const float* __restrict__ Aend, float* __restrict__ UT)
{
    __shared__ float As[L][68];
    __shared__ float Bs[L][68];

    const int bm   = blockIdx.x;
    const int tile = blockIdx.y;
    const int cb   = (tile >> 2) * 64;
    const int rb   = (tile & 3) * 64;
    const int b    = bm >> 5;
    const int m    = bm & 31;
    const size_t kb = (size_t)b * Sn * Dn + (size_t)m * L * Dn;
    const int tid = threadIdx.x;

    #pragma unroll
    for (int n = 0; n < 8; ++n) {
        const int e  = n * 256 + tid;
        const int sg = e >> 6;
        const int cc = e & 63;
        As[sg][cc] = Pk[kb + (size_t)sg * Dn + cb + cc];
        Bs[sg][cc] = Vt[kb + (size_t)sg * Dn + rb + cc];
    }
    __syncthreads();

    const int tx = tid & 15;
    const int ty = tid >> 4;
    float acc[4][4];
    #pragma unroll
    for (int i = 0; i < 4; ++i)
        #pragma unroll
        for (int j = 0; j < 4; ++j) acc[i][j] = 0.0f;

    #pragma unroll
    for (int sg = 0; sg < L; ++sg) {
        const float4 a4 = *(const float4*)&As[sg][ty * 4];
        const float4 b4 = *(const float4*)&Bs[sg][tx * 4];
        const float aa[4] = {a4.x, a4.y, a4.z, a4.w};
        const float bb[4] = {b4.x, b4.y, b4.z, b4.w};
        #pragma unroll
        for (int i = 0; i < 4; ++i)
            #pragma unroll
            for (int j = 0; j < 4; ++j)
                acc[i][j] = fmaf(aa[i], bb[j], acc[i][j]);
    }

    const float4 g4 = *(const float4*)(Aend + (size_t)bm * Dn + rb + tx * 4);
    float* ub = UT + (size_t)bm * Dn * Dn;
    #pragma unroll
    for (int i = 0; i < 4; ++i) {
        float4 o;
        o.x = acc[i][0] * g4.x; o.y = acc[i][1] * g4.y;
        o.z = acc[i][2] * g4.z; o.w = acc[i][3] * g4.w;
        *(float4*)(ub + (size_t)(cb + ty * 4 + i) * Dn + rb + tx * 4) = o;
    }
}

// ---------------------------------------------------------------------------
// compose (v4): gx<32 -> state scan (8 floats/thread, two fma chains);
// gx 32/33 -> den blocks: recompute nin in registers (same per-element fmaf
// scan as before -> bit-identical) and compute g_den via a 64-lane butterfly
// whose reduction tree exactly reproduces the old num_gemm partial/atomic
// tree (B32(low half)+B32(high half); fp32 '+' commutes bitwise, so the old
// atomic add order never mattered). Grid (34, Bn).
// ---------------------------------------------------------------------------
__global__ __launch_bounds__(256) void compose(
    const float* __restrict__ UT, const float* __restrict__ Aend,
    const float* __restrict__ un, const float* __restrict__ Pq,
    const float* __restrict__ Gc, const float* __restrict__ Nt,
    float* __restrict__ CinT)
{
    const int gx = blockIdx.x;
    const int b  = blockIdx.y;
    const int tid = threadIdx.x;

    if (gx >= 32) {
        // ---- den blocks: each handles 16 chunks ----
        const int m0 = (gx - 32) * 16;
        const int lane = tid & 63;
        const int w    = tid >> 6;           // wave 0..3
        const int r4   = lane * 4;           // r = 4l..4l+3 (low 32 lanes = r<128)

        float4 nin4 = make_float4(0.f, 0.f, 0.f, 0.f);
        for (int m = 0; m < m0; ++m) {
            const size_t s = ((size_t)b * NSEG + m) * Dn + r4;
            const float4 a4 = *(const float4*)(Aend + s);
            const float4 u4 = *(const float4*)(un + s);
            nin4.x = fmaf(a4.x, nin4.x, u4.x);
            nin4.y = fmaf(a4.y, nin4.y, u4.y);
            nin4.z = fmaf(a4.z, nin4.z, u4.z);
            nin4.w = fmaf(a4.w, nin4.w, u4.w);
        }

        for (int m = m0; m < m0 + 16; ++m) {
            const size_t qb = (size_t)b * Sn * Dn + (size_t)m * L * Dn;
            #pragma unroll
            for (int j = 0; j < 8; ++j) {
                const int tau = w * 8 + j;
                const size_t off = qb + (size_t)tau * Dn + r4;
                const float4 g4 = *(const float4*)(Gc + off);
                const float4 q4 = *(const float4*)(Pq + off);
                const float4 n4 = *(const float4*)(Nt + off);
                float dp = q4.x * g4.x * (nin4.x + n4.x)
                         + q4.y * g4.y * (nin4.y + n4.y)
                         + q4.z * g4.z * (nin4.z + n4.z)
                         + q4.w * g4.w * (nin4.w + n4.w);
                #pragma unroll
                for (int s = 1; s < 64; s <<= 1)
                    dp += __shfl_xor(dp, s, 64);
                if (lane == 0)
                    g_den[b * Sn + m * L + tau] = dp;
            }
            // advance nin to the state before chunk m+1
            const size_t s = ((size_t)b * NSEG + m) * Dn + r4;
            const float4 a4 = *(const float4*)(Aend + s);
            const float4 u4 = *(const float4*)(un + s);
            nin4.x = fmaf(a4.x, nin4.x, u4.x);
            nin4.y = fmaf(a4.y, nin4.y, u4.y);
            nin4.z = fmaf(a4.z, nin4.z, u4.z);
            nin4.w = fmaf(a4.w, nin4.w, u4.w);
        }
        return;
    }

    const int id = gx * 256 + tid;       // 0..8191
    const int c  = id >> 5;              // 0..255
    const int r8 = (id & 31) * 8;        // 0..248

    float4 acc0 = make_float4(0.f, 0.f, 0.f, 0.f);
    float4 acc1 = make_float4(0.f, 0.f, 0.f, 0.f);
    for (int m = 0; m < NSEG; ++m) {
        const size_t bm  = (size_t)b * NSEG + m;
        const size_t idx = bm * Dn * Dn + (size_t)c * Dn + r8;
        const float4 a40 = *(const float4*)(Aend + bm * Dn + r8);
        const float4 a41 = *(const float4*)(Aend + bm * Dn + r8 + 4);
        const float4 u40 = *(const float4*)(UT + idx);
        const float4 u41 = *(const float4*)(UT + idx + 4);
        *(float4*)(CinT + idx)     = acc0;
        *(float4*)(CinT + idx + 4) = acc1;
        acc0.x = fmaf(a40.x, acc0.x, u40.x);
        acc0.y = fmaf(a40.y, acc0.y, u40.y);
        acc0.z = fmaf(a40.z, acc0.z, u40.z);
        acc0.w = fmaf(a40.w, acc0.w, u40.w);
        acc1.x = fmaf(a41.x, acc1.x, u41.x);
        acc1.y = fmaf(a41.y, acc1.y, u41.y);
        acc1.z = fmaf(a41.z, acc1.z, u41.z);
        acc1.w = fmaf(a41.w, acc1.w, u41.w);
    }
}

// ---------------------------------------------------------------------------
// num_gemm (v2): Pnum[τ,r] = G[τ,r]·( S@Ṽ + Q@Cin^T ); epilogue now applies
// invd (g_den precomputed by compose) and writes bf16 hi/lo directly —
// identical fp32 op sequence to old num_gemm + split_pn (bit-identical).
// ---------------------------------------------------------------------------
__global__ __launch_bounds__(256) void num_gemm(
    const float* __restrict__ Pq, const float* __restrict__ Vt,
    const float* __restrict__ Gc, const float* __restrict__ Ssm,
    const float* __restrict__ CinT,
    unsigned short* __restrict__ Ph, unsigned short* __restrict__ Pl)
{
    __shared__ float Sld[L][33];
    __shared__ float Qld[L][257];

    const int rb = blockIdx.x * 128;
    const int m  = blockIdx.y;
    const int b  = blockIdx.z;
    const size_t qb = (size_t)b * Sn * Dn + (size_t)m * L * Dn;
    const size_t ub = ((size_t)b * NSEG + m) * Dn * Dn;
    const size_t sb = ((size_t)b * NSEG + m) * L * L;
    const int tid = threadIdx.x;

    #pragma unroll
    for (int n = 0; n < 4; ++n) {
        const int e = n * 256 + tid;
        Sld[e >> 5][e & 31] = Ssm[sb + e];
    }
    #pragma unroll
    for (int n = 0; n < L; ++n)
        Qld[n][tid] = Pq[qb + (size_t)n * Dn + tid];
    __syncthreads();

    const int tx = tid & 31;
    const int ty = tid >> 5;
    const int r4 = rb + tx * 4;
    const int t4 = ty * 4;

    float4 acc[4];
    #pragma unroll
    for (int i = 0; i < 4; ++i) acc[i] = make_float4(0.f, 0.f, 0.f, 0.f);

    #pragma unroll 4
    for (int sg = 0; sg < L; ++sg) {
        const float4 v4 = *(const float4*)(Vt + qb + (size_t)sg * Dn + r4);
        #pragma unroll
        for (int i = 0; i < 4; ++i) {
            const float s = Sld[t4 + i][sg];
            acc[i].x = fmaf(s, v4.x, acc[i].x);
            acc[i].y = fmaf(s, v4.y, acc[i].y);
            acc[i].z = fmaf(s, v4.z, acc[i].z);
            acc[i].w = fmaf(s, v4.w, acc[i].w);
        }
    }

    #pragma unroll 8
    for (int c = 0; c < Dn; ++c) {
        const float4 ct = *(const float4*)(CinT + ub + (size_t)c * Dn + r4);
        #pragma unroll
        for (int i = 0; i < 4; ++i) {
            const float q = Qld[t4 + i][c];
            acc[i].x = fmaf(q, ct.x, acc[i].x);
            acc[i].y = fmaf(q, ct.y, acc[i].y);
            acc[i].z = fmaf(q, ct.z, acc[i].z);
            acc[i].w = fmaf(q, ct.w, acc[i].w);
        }
    }

    // epilogue: o = acc*G; v = o*invd; split to bf16 hi/lo (== old split_pn)
    #pragma unroll
    for (int i = 0; i < 4; ++i) {
        const float invd =
            1.0f / fmaxf(fabsf(g_den[b * Sn + m * L + t4 + i]), 1.0f);
        const size_t off = qb + (size_t)(t4 + i) * Dn + r4;
        const float4 g4 = *(const float4*)(Gc + off);
        float4 v;
        v.x = (acc[i].x * g4.x) * invd;
        v.y = (acc[i].y * g4.y) * invd;
        v.z = (acc[i].z * g4.z) * invd;
        v.w = (acc[i].w * g4.w) * invd;
        ushort4 h, l;
        h.x = f2bf(v.x); l.x = f2bf(v.x - bf2f(h.x));
        h.y = f2bf(v.y); l.y = f2bf(v.y - bf2f(h.y));
        h.z = f2bf(v.z); l.z = f2bf(v.z - bf2f(h.z));
        h.w = f2bf(v.w); l.w = f2bf(v.w - bf2f(h.w));
        *(ushort4*)(Ph + off) = h;
        *(ushort4*)(Pl + off) = l;
    }
}

} // anonymous namespace

extern "C" void kernel_launch(void* const* d_in, const int* in_sizes, int n_in,
                              void* d_out, int out_size, void* d_ws, size_t ws_size,
                              hipStream_t stream)
{
    const float* x  = (const float*)d_in[0];
    const float* Wq = (const float*)d_in[1];  const float* bq = (const float*)d_in[2];
    const float* Wk = (const float*)d_in[3];  const float* bk = (const float*)d_in[4];
    // d_in[5]=Wv, d_in[6]=bv unused (reference uses W_q for v)
    const float* Wf = (const float*)d_in[7];  const float* bf = (const float*)d_in[8];
    const float* Wi = (const float*)d_in[9];  const float* bi = (const float*)d_in[10];
    const float* Wo = (const float*)d_in[11]; const float* bo = (const float*)d_in[12];
    float* out = (float*)d_out;

    float* ws = (float*)d_ws;
    const size_t sz = (size_t)Mn * Dn;            // 2,097,152 floats (8 MB)
    float* Pq = ws;
    float* Pk = ws + sz;
    float* Pf = ws + 2 * sz;
    float* Pi = ws + 3 * sz;
    // ws + 4*sz (old Pn slot) now unused
    float* Gc = ws + 5 * sz;                      // G cumprod  [b,t,r]
    float* Vt = ws + 6 * sz;                      // Ṽ          [b,t,r]
    float* Nt = ws + 7 * sz;                      // Ñ cumsum   [b,t,r]
    float* UT   = ws + 8 * sz;                    // [b,m][c][r]  8*sz
    float* CinT = ws + 16 * sz;                   // [b,m][c][r]  8*sz
    float* Ssm  = ws + 24 * sz;                   // [b,m][τ][σ]  262144
    float* Aend = Ssm + (size_t)Bn * NSEG * L * L;
    float* un   = Aend + (size_t)Bn * NSEG * Dn;
    float* tail = un   + (size_t)Bn * NSEG * Dn;  // free region

    unsigned short* Xh = (unsigned short*)UT;                 // 4 MB
    unsigned short* Xl = Xh + sz;                             // 4 MB
    unsigned short* Wh = Xl + sz;                             // 0.5 MB
    unsigned short* Wl = Wh + (size_t)1024 * Dn;              // 0.5 MB
    unsigned short* Ph  = (unsigned short*)UT;                // reuse after compose
    unsigned short* Pl  = Ph + sz;
    unsigned short* Woh = (unsigned short*)tail;              // persists to out_gemm
    unsigned short* Wol = Woh + (size_t)Dn * Dn;

    split_xw<<<dim3(2368), 256, 0, stream>>>(
        x, Wq, Wk, Wf, Wi, Wo, Xh, Xl, Wh, Wl, Woh, Wol);

    proj_gemm2<<<dim3(Mn / 128, 8), 256, 0, stream>>>(
        Xh, Xl, Wh, Wl, bq, bk, bf, bi, Pq, Pk, Pf, Pi);

    prep<<<dim3(NSEG, Bn), 512, 0, stream>>>(
        Pf, Pi, Pk, Pq, Gc, Vt, Nt, Aend, un, Ssm);

    ut_gemm<<<dim3(Bn * NSEG, 16), 256, 0, stream>>>(Pk, Vt, Aend, UT);

    compose<<<dim3(34, Bn), 256, 0, stream>>>(
        UT, Aend, un, Pq, Gc, Nt, CinT);

    num_gemm<<<dim3(2, NSEG, Bn), 256, 0, stream>>>(
        Pq, Vt, Gc, Ssm, CinT, Ph, Pl);

    out_gemm2<<<dim3(Mn / 64, Dn / 64), 256, 0, stream>>>(
        Ph, Pl, Woh, Wol, bo, out);
}

// Round 11
// 200.259 us; speedup vs baseline: 1.2611x; 1.2611x over previous
//
#include <hip/hip_runtime.h>
#include <math.h>

namespace {

constexpr int Bn = 8;
constexpr int Sn = 1024;
constexpr int Dn = 256;
constexpr int Mn = Bn * Sn;    // 8192 rows
constexpr int L  = 32;         // chunk length
constexpr int NSEG = Sn / L;   // 32 chunks

typedef __attribute__((ext_vector_type(8))) short short8;   // 8 bf16 (4 VGPRs)
typedef __attribute__((ext_vector_type(4))) float f32x4;    // MFMA acc

__device__ float g_den[Bn * Sn];   // n·q per (b,t); written by compose den-blocks

__device__ __forceinline__ float sigmoidf_(float x) {
    return 1.0f / (1.0f + __expf(-x));
}

__device__ __forceinline__ unsigned short f2bf(float x) {
    unsigned int u = __float_as_uint(x);
    return (unsigned short)((u + 0x7FFF + ((u >> 16) & 1)) >> 16);   // RNE
}
__device__ __forceinline__ float bf2f(unsigned short h) {
    return __uint_as_float(((unsigned int)h) << 16);
}

// ---------------------------------------------------------------------------
// split_xw: one-time fp32 -> bf16 hi/lo split of X, packed {Wq,Wk,Wf,Wi},
// and Wo. Grid 2368 blocks.
// ---------------------------------------------------------------------------
__global__ __launch_bounds__(256) void split_xw(
    const float* __restrict__ X,
    const float* __restrict__ Wq, const float* __restrict__ Wk,
    const float* __restrict__ Wf, const float* __restrict__ Wi,
    const float* __restrict__ Wo,
    unsigned short* __restrict__ Xh, unsigned short* __restrict__ Xl,
    unsigned short* __restrict__ Wh, unsigned short* __restrict__ Wl,
    unsigned short* __restrict__ Woh, unsigned short* __restrict__ Wol)
{
    const int i = blockIdx.x * 256 + threadIdx.x;
    const float4* src;
    unsigned short* dh;
    unsigned short* dl;
    size_t off;
    if (i < 524288) {
        src = (const float4*)X + i;
        dh = Xh; dl = Xl;
        off = (size_t)i * 4;
    } else if (i < 589824) {
        const int j = i - 524288;          // 0..65535
        const int w = j >> 14;             // which weight
        const int r = j & 16383;           // float4 within weight
        const float* Wp = (w == 0) ? Wq : (w == 1) ? Wk : (w == 2) ? Wf : Wi;
        src = (const float4*)Wp + r;
        dh = Wh; dl = Wl;
        off = ((size_t)w << 16) + (size_t)r * 4;
    } else {
        const int j = i - 589824;          // 0..16383
        src = (const float4*)Wo + j;
        dh = Woh; dl = Wol;
        off = (size_t)j * 4;
    }
    const float4 v = *src;
    ushort4 h, l;
    h.x = f2bf(v.x); l.x = f2bf(v.x - bf2f(h.x));
    h.y = f2bf(v.y); l.y = f2bf(v.y - bf2f(h.y));
    h.z = f2bf(v.z); l.z = f2bf(v.z - bf2f(h.z));
    h.w = f2bf(v.w); l.w = f2bf(v.w - bf2f(h.w));
    *(ushort4*)(dh + off) = h;
    *(ushort4*)(dl + off) = l;
}

// ---------------------------------------------------------------------------
// proj_gemm2: pure-bf16 MFMA x3 projection GEMM (r5 exact, 201.5us config).
// 128x128 tile, BK=32, register prefetch of next K-tile.
// ---------------------------------------------------------------------------
__global__ __launch_bounds__(256) void proj_gemm2(
    const unsigned short* __restrict__ Xh, const unsigned short* __restrict__ Xl,
    const unsigned short* __restrict__ Wh, const unsigned short* __restrict__ Wl,
    const float* __restrict__ b0, const float* __restrict__ b1,
    const float* __restrict__ b2, const float* __restrict__ b3,
    float* __restrict__ Y0, float* __restrict__ Y1,
    float* __restrict__ Y2, float* __restrict__ Y3)
{
    __shared__ unsigned short Ahs[128][40];
    __shared__ unsigned short Als[128][40];
    __shared__ unsigned short Bhs[128][40];
    __shared__ unsigned short Bls[128][40];

    const int tid = threadIdx.x;
    const int mb  = blockIdx.x * 128;
    const int nbg = blockIdx.y;            // 0..7
    const int widx = nbg >> 1;
    const int ro   = (nbg & 1) * 128;

    const float* bsel = (widx == 0) ? b0 : (widx == 1) ? b1 : (widx == 2) ? b2 : b3;
    float*       Ysel = (widx == 0) ? Y0 : (widx == 1) ? Y1 : (widx == 2) ? Y2 : Y3;

    const int lane = tid & 63;
    const int wv   = tid >> 6;
    const int wm   = (wv >> 1) * 64;
    const int wn   = (wv & 1) * 64;
    const int quad = lane >> 4;
    const int l16  = lane & 15;
    const int srow = tid >> 1;
    const int skq  = (tid & 1) * 16;

    const size_t abase = (size_t)(mb + srow) * Dn + skq;
    const size_t bbase = (size_t)(nbg * 128 + srow) * Dn + skq;

    f32x4 acc[4][4];
    #pragma unroll
    for (int mt = 0; mt < 4; ++mt)
        #pragma unroll
        for (int nt = 0; nt < 4; ++nt)
            acc[mt][nt] = (f32x4){0.f, 0.f, 0.f, 0.f};

    short8 pah0, pah1, pal0, pal1, pbh0, pbh1, pbl0, pbl1;
    pah0 = *(const short8*)(Xh + abase);     pah1 = *(const short8*)(Xh + abase + 8);
    pal0 = *(const short8*)(Xl + abase);     pal1 = *(const short8*)(Xl + abase + 8);
    pbh0 = *(const short8*)(Wh + bbase);     pbh1 = *(const short8*)(Wh + bbase + 8);
    pbl0 = *(const short8*)(Wl + bbase);     pbl1 = *(const short8*)(Wl + bbase + 8);

    for (int k0 = 0; k0 < Dn; k0 += 32) {
        __syncthreads();
        *(short8*)&Ahs[srow][skq]     = pah0;
        *(short8*)&Ahs[srow][skq + 8] = pah1;
        *(short8*)&Als[srow][skq]     = pal0;
        *(short8*)&Als[srow][skq + 8] = pal1;
        *(short8*)&Bhs[srow][skq]     = pbh0;
        *(short8*)&Bhs[srow][skq + 8] = pbh1;
        *(short8*)&Bls[srow][skq]     = pbl0;
        *(short8*)&Bls[srow][skq + 8] = pbl1;
        __syncthreads();

        if (k0 + 32 < Dn) {
            const size_t ka = abase + k0 + 32;
            const size_t kb = bbase + k0 + 32;
            pah0 = *(const short8*)(Xh + ka); pah1 = *(const short8*)(Xh + ka + 8);
            pal0 = *(const short8*)(Xl + ka); pal1 = *(const short8*)(Xl + ka + 8);
            pbh0 = *(const short8*)(Wh + kb); pbh1 = *(const short8*)(Wh + kb + 8);
            pbl0 = *(const short8*)(Wl + kb); pbl1 = *(const short8*)(Wl + kb + 8);
        }

        short8 afh[4], afl[4];
        #pragma unroll
        for (int mt = 0; mt < 4; ++mt) {
            const int row = wm + mt * 16 + l16;
            afh[mt] = *(const short8*)&Ahs[row][quad * 8];
            afl[mt] = *(const short8*)&Als[row][quad * 8];
        }
        #pragma unroll
        for (int nt = 0; nt < 4; ++nt) {
            const int row = wn + nt * 16 + l16;
            const short8 bfh = *(const short8*)&Bhs[row][quad * 8];
            const short8 bfl = *(const short8*)&Bls[row][quad * 8];
            #pragma unroll
            for (int mt = 0; mt < 4; ++mt) {
                acc[mt][nt] = __builtin_amdgcn_mfma_f32_16x16x32_bf16(
                    afh[mt], bfh, acc[mt][nt], 0, 0, 0);
                acc[mt][nt] = __builtin_amdgcn_mfma_f32_16x16x32_bf16(
                    afh[mt], bfl, acc[mt][nt], 0, 0, 0);
                acc[mt][nt] = __builtin_amdgcn_mfma_f32_16x16x32_bf16(
                    afl[mt], bfh, acc[mt][nt], 0, 0, 0);
            }
        }
    }

    #pragma unroll
    for (int nt = 0; nt < 4; ++nt) {
        const int col = ro + wn + nt * 16 + l16;
        const float bv = bsel[col];
        #pragma unroll
        for (int mt = 0; mt < 4; ++mt) {
            const int rowb = mb + wm + mt * 16 + quad * 4;
            #pragma unroll
            for (int r = 0; r < 4; ++r) {
                float v = acc[mt][nt][r] + bv;
                if (widx == 2)      v = sigmoidf_(v);
                else if (widx == 3) v = __expf(v);
                Ysel[(size_t)(rowb + r) * Dn + col] = v;
            }
        }
    }
}

// ---------------------------------------------------------------------------
// out_gemm2: pure-bf16 MFMA x3 output GEMM (r5 exact). 64x64, grid (128,4).
// ---------------------------------------------------------------------------
__global__ __launch_bounds__(256) void out_gemm2(
    const unsigned short* __restrict__ Ph, const unsigned short* __restrict__ Pl,
    const unsigned short* __restrict__ Woh, const unsigned short* __restrict__ Wol,
    const float* __restrict__ bias, float* __restrict__ Y)
{
    __shared__ unsigned short Ahs[64][40];
    __shared__ unsigned short Als[64][40];
    __shared__ unsigned short Bhs[64][40];
    __shared__ unsigned short Bls[64][40];

    const int tid = threadIdx.x;
    const int mb  = blockIdx.x * 64;
    const int nb  = blockIdx.y * 64;

    const int lane = tid & 63;
    const int wv   = tid >> 6;
    const int wm   = (wv >> 1) * 32;
    const int wn   = (wv & 1) * 32;
    const int quad = lane >> 4;
    const int l16  = lane & 15;
    const int srow = tid >> 2;
    const int skq  = (tid & 3) * 8;

    const size_t abase = (size_t)(mb + srow) * Dn + skq;
    const size_t bbase = (size_t)(nb + srow) * Dn + skq;

    f32x4 acc[2][2];
    #pragma unroll
    for (int mt = 0; mt < 2; ++mt)
        #pragma unroll
        for (int nt = 0; nt < 2; ++nt)
            acc[mt][nt] = (f32x4){0.f, 0.f, 0.f, 0.f};

    short8 pah, pal, pbh, pbl;
    pah = *(const short8*)(Ph  + abase);
    pal = *(const short8*)(Pl  + abase);
    pbh = *(const short8*)(Woh + bbase);
    pbl = *(const short8*)(Wol + bbase);

    for (int k0 = 0; k0 < Dn; k0 += 32) {
        __syncthreads();
        *(short8*)&Ahs[srow][skq] = pah;
        *(short8*)&Als[srow][skq] = pal;
        *(short8*)&Bhs[srow][skq] = pbh;
        *(short8*)&Bls[srow][skq] = pbl;
        __syncthreads();

        if (k0 + 32 < Dn) {
            const size_t ka = abase + k0 + 32;
            const size_t kb = bbase + k0 + 32;
            pah = *(const short8*)(Ph  + ka);
            pal = *(const short8*)(Pl  + ka);
            pbh = *(const short8*)(Woh + kb);
            pbl = *(const short8*)(Wol + kb);
        }

        short8 afh[2], afl[2];
        #pragma unroll
        for (int mt = 0; mt < 2; ++mt) {
            const int row = wm + mt * 16 + l16;
            afh[mt] = *(const short8*)&Ahs[row][quad * 8];
            afl[mt] = *(const short8*)&Als[row][quad * 8];
        }
        #pragma unroll
        for (int nt = 0; nt < 2; ++nt) {
            const int row = wn + nt * 16 + l16;
            const short8 bfh = *(const short8*)&Bhs[row][quad * 8];
            const short8 bfl = *(const short8*)&Bls[row][quad * 8];
            #pragma unroll
            for (int mt = 0; mt < 2; ++mt) {
                acc[mt][nt] = __builtin_amdgcn_mfma_f32_16x16x32_bf16(
                    afh[mt], bfh, acc[mt][nt], 0, 0, 0);
                acc[mt][nt] = __builtin_amdgcn_mfma_f32_16x16x32_bf16(
                    afh[mt], bfl, acc[mt][nt], 0, 0, 0);
                acc[mt][nt] = __builtin_amdgcn_mfma_f32_16x16x32_bf16(
                    afl[mt], bfh, acc[mt][nt], 0, 0, 0);
            }
        }
    }

    #pragma unroll
    for (int nt = 0; nt < 2; ++nt) {
        const int col = nb + wn + nt * 16 + l16;
        const float bv = bias[col];
        #pragma unroll
        for (int mt = 0; mt < 2; ++mt) {
            const int rowb = mb + wm + mt * 16 + quad * 4;
            #pragma unroll
            for (int r = 0; r < 4; ++r) {
                Y[(size_t)(rowb + r) * Dn + col] = acc[mt][nt][r] + bv;
            }
        }
    }
}

// ---------------------------------------------------------------------------
// prep (v2): 512 threads, wave-specialized (gate scan || masked QK^T).
// ---------------------------------------------------------------------------
__global__ __launch_bounds__(512) void prep(
    const float* __restrict__ Pf, const float* __restrict__ Pi,
    const float* __restrict__ Pk, const float* __restrict__ Pq,
    float* __restrict__ Gc, float* __restrict__ Vt, float* __restrict__ Nt,
    float* __restrict__ Aend, float* __restrict__ un, float* __restrict__ Ssm)
{
    __shared__ float Ks[L][260];   // K chunk, row-major, +4 pad
    __shared__ float Qs[L][260];   // Q chunk

    const int m = blockIdx.x;
    const int b = blockIdx.y;
    const int tid = threadIdx.x;
    const size_t qb = (size_t)b * Sn * Dn + (size_t)m * L * Dn;

    #pragma unroll
    for (int p = 0; p < 4; ++p) {
        const int lin = p * 512 + tid;           // 0..2047
        const int row = lin >> 6;
        const int c4  = (lin & 63) * 4;
        *(float4*)&Ks[row][c4] = *(const float4*)(Pk + qb + (size_t)row * Dn + c4);
    }
    #pragma unroll
    for (int p = 0; p < 4; ++p) {
        const int lin = p * 512 + tid;
        const int row = lin >> 6;
        const int c4  = (lin & 63) * 4;
        *(float4*)&Qs[row][c4] = *(const float4*)(Pq + qb + (size_t)row * Dn + c4);
    }
    __syncthreads();

    if (tid < 256) {
        // ---- phase A: gate scan, thread = column r; f/i batched 8-deep ----
        const int r = tid;
        const size_t base = qb + r;
        float G = 1.0f, Nacc = 0.0f;
        for (int tb = 0; tb < L; tb += 8) {
            float fv[8], iv[8];
            #pragma unroll
            for (int u = 0; u < 8; ++u) {
                fv[u] = Pf[base + (size_t)(tb + u) * Dn];
                iv[u] = Pi[base + (size_t)(tb + u) * Dn];
            }
            #pragma unroll
            for (int u = 0; u < 8; ++u) {
                const int t = tb + u;
                const size_t off = base + (size_t)t * Dn;
                const float kv = Ks[t][r];
                const float vv = Qs[t][r];
                G *= fv[u];
                const float rG = 1.0f / G;
                Gc[off] = G;
                Vt[off] = iv[u] * vv * rG;
                Nacc = fmaf(iv[u] * kv, rG, Nacc);
                Nt[off] = Nacc;
            }
        }
        const size_t s = ((size_t)b * NSEG + m) * Dn + r;
        Aend[s] = G;
        un[s]   = G * Nacc;
    } else {
        // ---- phase B: S = masked QK^T from LDS ----
        const int t2  = tid - 256;
        const int tau = t2 >> 3;
        const int sb0 = t2 & 7;                  // sigma = sb0 + 8j, j=0..3

        float a0 = 0.f, a1 = 0.f, a2 = 0.f, a3 = 0.f;
        #pragma unroll 4
        for (int c = 0; c < Dn; c += 4) {
            const float4 q4 = *(const float4*)&Qs[tau][c];
            const float4 k0 = *(const float4*)&Ks[sb0     ][c];
            const float4 k1 = *(const float4*)&Ks[sb0 +  8][c];
            const float4 k2 = *(const float4*)&Ks[sb0 + 16][c];
            const float4 k3 = *(const float4*)&Ks[sb0 + 24][c];
            a0 += q4.x*k0.x + q4.y*k0.y + q4.z*k0.z + q4.w*k0.w;
            a1 += q4.x*k1.x + q4.y*k1.y + q4.z*k1.z + q4.w*k1.w;
            a2 += q4.x*k2.x + q4.y*k2.y + q4.z*k2.z + q4.w*k2.w;
            a3 += q4.x*k3.x + q4.y*k3.y + q4.z*k3.z + q4.w*k3.w;
        }
        float* outp = Ssm + ((size_t)b * NSEG + m) * L * L + (size_t)tau * L;
        outp[sb0     ] = (sb0      <= tau) ? a0 : 0.0f;
        outp[sb0 +  8] = (sb0 +  8 <= tau) ? a1 : 0.0f;
        outp[sb0 + 16] = (sb0 + 16 <= tau) ? a2 : 0.0f;
        outp[sb0 + 24] = (sb0 + 24 <= tau) ? a3 : 0.0f;
    }
}

// ---------------------------------------------------------------------------
// ut_gemm: UT[b,m][c,r] = Aend[r] * Σ_σ K[σ,c]·Ṽ[σ,r]
// ---------------------------------------------------------------------------
__global__ __launch_bounds__(256) void ut_gemm(
    const float* __restrict__ Pk, const float* __restrict__ Vt,
    const float* __restrict__ Aend, float* __restrict__ UT)
{
    __shared__ float As[L][68];
    __shared__ float Bs[L][68];

    const int bm   = blockIdx.x;
    const int tile = blockIdx.y;
    const int cb   = (tile >> 2) * 64;
    const int rb   = (tile & 3) * 64;
    const int b    = bm >> 5;
    const int m    = bm & 31;
    const size_t kb = (size_t)b * Sn * Dn + (size_t)m * L * Dn;
    const int tid = threadIdx.x;

    #pragma unroll
    for (int n = 0; n < 8; ++n) {
        const int e  = n * 256 + tid;
        const int sg = e >> 6;
        const int cc = e & 63;
        As[sg][cc] = Pk[kb + (size_t)sg * Dn + cb + cc];
        Bs[sg][cc] = Vt[kb + (size_t)sg * Dn + rb + cc];
    }
    __syncthreads();

    const int tx = tid & 15;
    const int ty = tid >> 4;
    float acc[4][4];
    #pragma unroll
    for (int i = 0; i < 4; ++i)
        #pragma unroll
        for (int j = 0; j < 4; ++j) acc[i][j] = 0.0f;

    #pragma unroll
    for (int sg = 0; sg < L; ++sg) {
        const float4 a4 = *(const float4*)&As[sg][ty * 4];
        const float4 b4 = *(const float4*)&Bs[sg][tx * 4];
        const float aa[4] = {a4.x, a4.y, a4.z, a4.w};
        const float bb[4] = {b4.x, b4.y, b4.z, b4.w};
        #pragma unroll
        for (int i = 0; i < 4; ++i)
            #pragma unroll
            for (int j = 0; j < 4; ++j)
                acc[i][j] = fmaf(aa[i], bb[j], acc[i][j]);
    }

    const float4 g4 = *(const float4*)(Aend + (size_t)bm * Dn + rb + tx * 4);
    float* ub = UT + (size_t)bm * Dn * Dn;
    #pragma unroll
    for (int i = 0; i < 4; ++i) {
        float4 o;
        o.x = acc[i][0] * g4.x; o.y = acc[i][1] * g4.y;
        o.z = acc[i][2] * g4.z; o.w = acc[i][3] * g4.w;
        *(float4*)(ub + (size_t)(cb + ty * 4 + i) * Dn + rb + tx * 4) = o;
    }
}

// ---------------------------------------------------------------------------
// compose (v5): gx<32 -> state scan (8 floats/thread, two fma chains);
// gx in [32,64) -> den block for chunk m = gx-32 (ONE chunk per block,
// 256 den blocks total vs r9's 16 — kills the serialization tail).
// Per-(m,tau) math identical to r9 (prescan fmaf chain, dp expression,
// 64-lane butterfly == old B32(low)+B32(high) atomic tree) -> bit-identical.
// Grid (64, Bn).
// ---------------------------------------------------------------------------
__global__ __launch_bounds__(256) void compose(
    const float* __restrict__ UT, const float* __restrict__ Aend,
    const float* __restrict__ un, const float* __restrict__ Pq,
    const float* __restrict__ Gc, const float* __restrict__ Nt,
    float* __restrict__ CinT)
{
    const int gx = blockIdx.x;
    const int b  = blockIdx.y;
    const int tid = threadIdx.x;

    if (gx >= 32) {
        // ---- den block: exactly one chunk m ----
        const int m = gx - 32;
        const int lane = tid & 63;
        const int w    = tid >> 6;           // wave 0..3
        const int r4   = lane * 4;           // r = 4l..4l+3

        // prescan: nin at the start of chunk m (same fmaf chain as r9)
        float4 nin4 = make_float4(0.f, 0.f, 0.f, 0.f);
        for (int mm = 0; mm < m; ++mm) {
            const size_t s = ((size_t)b * NSEG + mm) * Dn + r4;
            const float4 a4 = *(const float4*)(Aend + s);
            const float4 u4 = *(const float4*)(un + s);
            nin4.x = fmaf(a4.x, nin4.x, u4.x);
            nin4.y = fmaf(a4.y, nin4.y, u4.y);
            nin4.z = fmaf(a4.z, nin4.z, u4.z);
            nin4.w = fmaf(a4.w, nin4.w, u4.w);
        }

        const size_t qb = (size_t)b * Sn * Dn + (size_t)m * L * Dn;
        #pragma unroll
        for (int j = 0; j < 8; ++j) {
            const int tau = w * 8 + j;
            const size_t off = qb + (size_t)tau * Dn + r4;
            const float4 g4 = *(const float4*)(Gc + off);
            const float4 q4 = *(const float4*)(Pq + off);
            const float4 n4 = *(const float4*)(Nt + off);
            float dp = q4.x * g4.x * (nin4.x + n4.x)
                     + q4.y * g4.y * (nin4.y + n4.y)
                     + q4.z * g4.z * (nin4.z + n4.z)
                     + q4.w * g4.w * (nin4.w + n4.w);
            #pragma unroll
            for (int s = 1; s < 64; s <<= 1)
                dp += __shfl_xor(dp, s, 64);
            if (lane == 0)
                g_den[b * Sn + m * L + tau] = dp;
        }
        return;
    }

    const int id = gx * 256 + tid;       // 0..8191
    const int c  = id >> 5;              // 0..255
    const int r8 = (id & 31) * 8;        // 0..248

    float4 acc0 = make_float4(0.f, 0.f, 0.f, 0.f);
    float4 acc1 = make_float4(0.f, 0.f, 0.f, 0.f);
    for (int m = 0; m < NSEG; ++m) {
        const size_t bm  = (size_t)b * NSEG + m;
        const size_t idx = bm * Dn * Dn + (size_t)c * Dn + r8;
        const float4 a40 = *(const float4*)(Aend + bm * Dn + r8);
        const float4 a41 = *(const float4*)(Aend + bm * Dn + r8 + 4);
        const float4 u40 = *(const float4*)(UT + idx);
        const float4 u41 = *(const float4*)(UT + idx + 4);
        *(float4*)(CinT + idx)     = acc0;
        *(float4*)(CinT + idx + 4) = acc1;
        acc0.x = fmaf(a40.x, acc0.x, u40.x);
        acc0.y = fmaf(a40.y, acc0.y, u40.y);
        acc0.z = fmaf(a40.z, acc0.z, u40.z);
        acc0.w = fmaf(a40.w, acc0.w, u40.w);
        acc1.x = fmaf(a41.x, acc1.x, u41.x);
        acc1.y = fmaf(a41.y, acc1.y, u41.y);
        acc1.z = fmaf(a41.z, acc1.z, u41.z);
        acc1.w = fmaf(a41.w, acc1.w, u41.w);
    }
}

// ---------------------------------------------------------------------------
// num_gemm (v2): Pnum[τ,r] = G[τ,r]·( S@Ṽ + Q@Cin^T ); epilogue applies
// invd (g_den precomputed by compose) and writes bf16 hi/lo directly —
// identical fp32 op sequence to old num_gemm + split_pn (bit-identical).
// ---------------------------------------------------------------------------
__global__ __launch_bounds__(256) void num_gemm(
    const float* __restrict__ Pq, const float* __restrict__ Vt,
    const float* __restrict__ Gc, const float* __restrict__ Ssm,
    const float* __restrict__ CinT,
    unsigned short* __restrict__ Ph, unsigned short* __restrict__ Pl)
{
    __shared__ float Sld[L][33];
    __shared__ float Qld[L][257];

    const int rb = blockIdx.x * 128;
    const int m  = blockIdx.y;
    const int b  = blockIdx.z;
    const size_t qb = (size_t)b * Sn * Dn + (size_t)m * L * Dn;
    const size_t ub = ((size_t)b * NSEG + m) * Dn * Dn;
    const size_t sb = ((size_t)b * NSEG + m) * L * L;
    const int tid = threadIdx.x;

    #pragma unroll
    for (int n = 0; n < 4; ++n) {
        const int e = n * 256 + tid;
        Sld[e >> 5][e & 31] = Ssm[sb + e];
    }
    #pragma unroll
    for (int n = 0; n < L; ++n)
        Qld[n][tid] = Pq[qb + (size_t)n * Dn + tid];
    __syncthreads();

    const int tx = tid & 31;
    const int ty = tid >> 5;
    const int r4 = rb + tx * 4;
    const int t4 = ty * 4;

    float4 acc[4];
    #pragma unroll
    for (int i = 0; i < 4; ++i) acc[i] = make_float4(0.f, 0.f, 0.f, 0.f);

    #pragma unroll 4
    for (int sg = 0; sg < L; ++sg) {
        const float4 v4 = *(const float4*)(Vt + qb + (size_t)sg * Dn + r4);
        #pragma unroll
        for (int i = 0; i < 4; ++i) {
            const float s = Sld[t4 + i][sg];
            acc[i].x = fmaf(s, v4.x, acc[i].x);
            acc[i].y = fmaf(s, v4.y, acc[i].y);
            acc[i].z = fmaf(s, v4.z, acc[i].z);
            acc[i].w = fmaf(s, v4.w, acc[i].w);
        }
    }

    #pragma unroll 8
    for (int c = 0; c < Dn; ++c) {
        const float4 ct = *(const float4*)(CinT + ub + (size_t)c * Dn + r4);
        #pragma unroll
        for (int i = 0; i < 4; ++i) {
            const float q = Qld[t4 + i][c];
            acc[i].x = fmaf(q, ct.x, acc[i].x);
            acc[i].y = fmaf(q, ct.y, acc[i].y);
            acc[i].z = fmaf(q, ct.z, acc[i].z);
            acc[i].w = fmaf(q, ct.w, acc[i].w);
        }
    }

    // epilogue: o = acc*G; v = o*invd; split to bf16 hi/lo (== old split_pn)
    #pragma unroll
    for (int i = 0; i < 4; ++i) {
        const float invd =
            1.0f / fmaxf(fabsf(g_den[b * Sn + m * L + t4 + i]), 1.0f);
        const size_t off = qb + (size_t)(t4 + i) * Dn + r4;
        const float4 g4 = *(const float4*)(Gc + off);
        float4 v;
        v.x = (acc[i].x * g4.x) * invd;
        v.y = (acc[i].y * g4.y) * invd;
        v.z = (acc[i].z * g4.z) * invd;
        v.w = (acc[i].w * g4.w) * invd;
        ushort4 h, l;
        h.x = f2bf(v.x); l.x = f2bf(v.x - bf2f(h.x));
        h.y = f2bf(v.y); l.y = f2bf(v.y - bf2f(h.y));
        h.z = f2bf(v.z); l.z = f2bf(v.z - bf2f(h.z));
        h.w = f2bf(v.w); l.w = f2bf(v.w - bf2f(h.w));
        *(ushort4*)(Ph + off) = h;
        *(ushort4*)(Pl + off) = l;
    }
}

} // anonymous namespace

extern "C" void kernel_launch(void* const* d_in, const int* in_sizes, int n_in,
                              void* d_out, int out_size, void* d_ws, size_t ws_size,
                              hipStream_t stream)
{
    const float* x  = (const float*)d_in[0];
    const float* Wq = (const float*)d_in[1];  const float* bq = (const float*)d_in[2];
    const float* Wk = (const float*)d_in[3];  const float* bk = (const float*)d_in[4];
    // d_in[5]=Wv, d_in[6]=bv unused (reference uses W_q for v)
    const float* Wf = (const float*)d_in[7];  const float* bf = (const float*)d_in[8];
    const float* Wi = (const float*)d_in[9];  const float* bi = (const float*)d_in[10];
    const float* Wo = (const float*)d_in[11]; const float* bo = (const float*)d_in[12];
    float* out = (float*)d_out;

    float* ws = (float*)d_ws;
    const size_t sz = (size_t)Mn * Dn;            // 2,097,152 floats (8 MB)
    float* Pq = ws;
    float* Pk = ws + sz;
    float* Pf = ws + 2 * sz;
    float* Pi = ws + 3 * sz;
    // ws + 4*sz (old Pn slot) unused
    float* Gc = ws + 5 * sz;                      // G cumprod  [b,t,r]
    float* Vt = ws + 6 * sz;                      // Ṽ          [b,t,r]
    float* Nt = ws + 7 * sz;                      // Ñ cumsum   [b,t,r]
    float* UT   = ws + 8 * sz;                    // [b,m][c][r]  8*sz
    float* CinT = ws + 16 * sz;                   // [b,m][c][r]  8*sz
    float* Ssm  = ws + 24 * sz;                   // [b,m][τ][σ]  262144
    float* Aend = Ssm + (size_t)Bn * NSEG * L * L;
    float* un   = Aend + (size_t)Bn * NSEG * Dn;
    float* tail = un   + (size_t)Bn * NSEG * Dn;  // free region

    unsigned short* Xh = (unsigned short*)UT;                 // 4 MB
    unsigned short* Xl = Xh + sz;                             // 4 MB
    unsigned short* Wh = Xl + sz;                             // 0.5 MB
    unsigned short* Wl = Wh + (size_t)1024 * Dn;              // 0.5 MB
    unsigned short* Ph  = (unsigned short*)UT;                // reuse after compose
    unsigned short* Pl  = Ph + sz;
    unsigned short* Woh = (unsigned short*)tail;              // persists to out_gemm
    unsigned short* Wol = Woh + (size_t)Dn * Dn;

    split_xw<<<dim3(2368), 256, 0, stream>>>(
        x, Wq, Wk, Wf, Wi, Wo, Xh, Xl, Wh, Wl, Woh, Wol);

    proj_gemm2<<<dim3(Mn / 128, 8), 256, 0, stream>>>(
        Xh, Xl, Wh, Wl, bq, bk, bf, bi, Pq, Pk, Pf, Pi);

    prep<<<dim3(NSEG, Bn), 512, 0, stream>>>(
        Pf, Pi, Pk, Pq, Gc, Vt, Nt, Aend, un, Ssm);

    ut_gemm<<<dim3(Bn * NSEG, 16), 256, 0, stream>>>(Pk, Vt, Aend, UT);

    compose<<<dim3(64, Bn), 256, 0, stream>>>(
        UT, Aend, un, Pq, Gc, Nt, CinT);

    num_gemm<<<dim3(2, NSEG, Bn), 256, 0, stream>>>(
        Pq, Vt, Gc, Ssm, CinT, Ph, Pl);

    out_gemm2<<<dim3(Mn / 64, Dn / 64), 256, 0, stream>>>(
        Ph, Pl, Woh, Wol, bo, out);
}